// Round 3
// baseline (245.257 us; speedup 1.0000x reference)
//
#include <hip/hip_runtime.h>

// RoiAlign (TF crop_and_resize style), fp32, NHWC.
// features: [B,H,W,C] = [2,64,64,256]; rois: [B,N,4] = [2,2000,4]
// out: [B,N,7,7,C]
//
// R4: LDS-binned two-pass design.
// Post-mortem of R3: y-band/XCD partitioning was NEUTRAL->worse (kernel
// ~91us -> ~103us; dur_us also includes a ~125us harness re-poison fill
// that dominates the top-5 dispatches). Cache-policy tricks (XCD swizzle,
// nt stores, y-banding) did not convert the 784 MB random gather stream
// into L2 hits. So: make the reuse explicit instead of hoping for it.
//
//   pass 0: zero 128 bin counters (tiny kernel, graph-capture safe)
//   pass 1: bin each output row (b,n,py) by (b, y0) -> 128 bins.
//           Rows in a bin touch ONLY feature rows {y0, y0+1} = 128 KB.
//           Slot cap = 14000 = rows/batch = hard bound -> no overflow.
//   pass 2: 128 bins x 8 blocks; each block (1024 thr, 128 KB LDS)
//           stages rows y0,y0+1 once, then serves all 4 corner reads of
//           its row-slice from LDS (contiguous ds_read_b128, conflict-
//           free). Stores stay NONTEMPORAL (200 MB stream).
//
// Read traffic: 784 MB random gather -> 128 MB sequential staging.
// Kernel chain becomes write-bound (~200 MB => ~32 us floor).
// Fallback: if ws_size < 7.2 MB, launch the proven direct kernel.

#define POOL  7
#define NBINS 128          // 2 batches * 64 y-rows
#define CAP   14000        // max rows per bin == rows per batch (hard bound)
#define BPB   8            // blocks per bin in pass 2

typedef float vfloat4 __attribute__((ext_vector_type(4)));

// ---------- pass 0: zero bin counters ----------
__global__ void zero_counts(int* __restrict__ counts) {
    if ((int)threadIdx.x < NBINS) counts[threadIdx.x] = 0;
}

// ---------- pass 1: bin output rows by (batch, y0) ----------
__global__ __launch_bounds__(256) void bin_rows(
    const float* __restrict__ rois,
    int* __restrict__ counts,
    int* __restrict__ slots,
    int H, int N)
{
    const int rows_per_batch = N * POOL;
    const int total = 2 * rows_per_batch;
    const int gid = blockIdx.x * 256 + threadIdx.x;
    if (gid >= total) return;

    const int b   = gid / rows_per_batch;
    const int rem = gid - b * rows_per_batch;      // n*POOL + py, 0..13999
    const int n   = rem / POOL;
    const int py  = rem - n * POOL;

    const float* r = rois + ((long long)b * N + n) * 4;
    const float ry1 = r[0], ry2 = r[2];

    // EXACT same FP sequence as pass 2 so y0 matches bit-identically.
    const float fy  = (float)py * (1.0f / (POOL - 1));
    const float ys  = (ry1 + fy * (ry2 - ry1)) * (float)(H - 1);
    const float y0f = fminf(fmaxf(floorf(ys), 0.0f), (float)(H - 1));
    const int   y0  = (int)y0f;

    const int bin = b * 64 + y0;
    const int idx = atomicAdd(&counts[bin], 1);    // idx < CAP guaranteed
    slots[bin * CAP + idx] = rem;
}

// ---------- pass 2: consume bins, corners from LDS ----------
__global__ __launch_bounds__(1024) void roialign_binned(
    const float* __restrict__ feat,   // [B,H,W,C]
    const float* __restrict__ rois,   // [B,N,4]
    float* __restrict__ out,          // [B,N,POOL,POOL,C]
    const int* __restrict__ counts,
    const int* __restrict__ slots,
    int H, int W, int C4, int N)
{
    __shared__ vfloat4 lds[2][64 * 64];   // [row][x*C4 + lane] : 2 x 64 KB

    const int bin = blockIdx.x >> 3;      // / BPB
    const int j   = blockIdx.x & (BPB - 1);
    const int count = counts[bin];
    const int s0 = (j * count) / BPB;     // contiguous slice of the bin
    const int s1 = ((j + 1) * count) / BPB;
    if (s0 >= s1) return;                 // uniform early-exit (covers count==0)

    const int b   = bin >> 6;
    const int y0  = bin & 63;
    const int y1i = min(y0 + 1, H - 1);

    // stage feature rows y0 and y1i (64 KB each) into LDS, coalesced
    const vfloat4* fb = (const vfloat4*)feat + (long long)b * H * W * C4;
    const vfloat4* g0 = fb + (long long)y0  * W * C4;
    const vfloat4* g1 = fb + (long long)y1i * W * C4;
    for (int t = threadIdx.x; t < W * C4; t += 1024) {  // W*C4 = 4096
        lds[0][t] = g0[t];
        lds[1][t] = g1[t];
    }
    __syncthreads();

    const int lane = threadIdx.x & 63;
    const int wid  = threadIdx.x >> 6;    // wave 0..15

    for (int i = s0 + wid; i < s1; i += 16) {
        const int rem = slots[bin * CAP + i];   // wave-uniform
        const int n   = rem / POOL;
        const int py  = rem - n * POOL;

        const float* r = rois + ((long long)b * N + n) * 4;
        const float ry1 = r[0], rx1 = r[1], ry2 = r[2], rx2 = r[3];

        const float fy  = (float)py * (1.0f / (POOL - 1));
        const float ys  = (ry1 + fy * (ry2 - ry1)) * (float)(H - 1);
        const float y0f = fminf(fmaxf(floorf(ys), 0.0f), (float)(H - 1));
        const float wy  = ys - y0f;             // y0f == (float)y0 by construction
        const float dx  = rx2 - rx1;

        vfloat4* ob = (vfloat4*)out +
            (((long long)b * N + n) * (POOL * POOL) + (long long)py * POOL) * C4 + lane;

#pragma unroll
        for (int px = 0; px < POOL; ++px) {
            const float fx  = (float)px * (1.0f / (POOL - 1));
            const float xs  = (rx1 + fx * dx) * (float)(W - 1);
            const float x0f = fminf(fmaxf(floorf(xs), 0.0f), (float)(W - 1));
            const int   x0  = (int)x0f;
            const int   x1i = min(x0 + 1, W - 1);
            const float wx  = xs - x0f;

            const vfloat4 f00 = lds[0][x0  * C4 + lane];
            const vfloat4 f01 = lds[0][x1i * C4 + lane];
            const vfloat4 f10 = lds[1][x0  * C4 + lane];
            const vfloat4 f11 = lds[1][x1i * C4 + lane];

            const vfloat4 top = f00 + (f01 - f00) * wx;
            const vfloat4 bot = f10 + (f11 - f10) * wx;
            const vfloat4 o   = top + (bot - top) * wy;

            __builtin_nontemporal_store(o, ob + px * C4);
        }
    }
}

// ---------- fallback: proven direct kernel (R2 structure, ~91 us) ----------
__global__ __launch_bounds__(256) void roialign_direct(
    const float* __restrict__ feat, const float* __restrict__ rois,
    float* __restrict__ out, int H, int W, int C4, int N, int blocks_per_batch)
{
    const int lane = threadIdx.x & 63;
    const int wid  = threadIdx.x >> 6;
    const int xcd  = blockIdx.x & 7;
    const int slot = blockIdx.x >> 3;
    const int b    = xcd >> 2;
    const int lblock = slot * 4 + (xcd & 3);
    if (lblock >= blocks_per_batch) return;
    const int row = lblock * 4 + wid;
    if (row >= N * POOL) return;
    const int n  = row / POOL;
    const int py = row - n * POOL;

    const float* r = rois + ((long long)b * N + n) * 4;
    const float ry1 = r[0], rx1 = r[1], ry2 = r[2], rx2 = r[3];
    const float fy  = (float)py * (1.0f / (POOL - 1));
    const float ys  = (ry1 + fy * (ry2 - ry1)) * (float)(H - 1);
    const float y0f = fminf(fmaxf(floorf(ys), 0.0f), (float)(H - 1));
    const int   y0  = (int)y0f;
    const int   y1i = min(y0 + 1, H - 1);
    const float wy  = ys - y0f;

    const vfloat4* fb = (const vfloat4*)feat + (long long)b * H * W * C4;
    const vfloat4* r0 = fb + (long long)y0  * W * C4 + lane;
    const vfloat4* r1 = fb + (long long)y1i * W * C4 + lane;
    vfloat4* ob = (vfloat4*)out +
        (((long long)b * N + n) * (POOL * POOL) + (long long)py * POOL) * C4 + lane;
    const float dx = rx2 - rx1;
#pragma unroll
    for (int px = 0; px < POOL; ++px) {
        const float fx  = (float)px * (1.0f / (POOL - 1));
        const float xs  = (rx1 + fx * dx) * (float)(W - 1);
        const float x0f = fminf(fmaxf(floorf(xs), 0.0f), (float)(W - 1));
        const int   x0  = (int)x0f;
        const int   x1i = min(x0 + 1, W - 1);
        const float wx  = xs - x0f;
        const vfloat4 f00 = r0[x0  * C4];
        const vfloat4 f01 = r0[x1i * C4];
        const vfloat4 f10 = r1[x0  * C4];
        const vfloat4 f11 = r1[x1i * C4];
        const vfloat4 top = f00 + (f01 - f00) * wx;
        const vfloat4 bot = f10 + (f11 - f10) * wx;
        const vfloat4 o   = top + (bot - top) * wy;
        __builtin_nontemporal_store(o, ob + px * C4);
    }
}

extern "C" void kernel_launch(void* const* d_in, const int* in_sizes, int n_in,
                              void* d_out, int out_size, void* d_ws, size_t ws_size,
                              hipStream_t stream) {
    const int B = 2, H = 64, W = 64, C = 256;
    const int N = in_sizes[1] / (B * 4);   // rois flat = B*N*4

    const float* feat = (const float*)d_in[0];
    const float* rois = (const float*)d_in[1];
    float* out = (float*)d_out;

    const size_t ws_needed = (size_t)NBINS * 4            // counts
                           + (size_t)NBINS * CAP * 4;     // slots (7.17 MB)

    if (ws_size >= ws_needed && d_ws != nullptr) {
        int* counts = (int*)d_ws;
        int* slots  = counts + NBINS;

        const int total_rows = B * N * POOL;              // 28000
        const int bin_blocks = (total_rows + 255) / 256;  // 110

        zero_counts<<<1, NBINS, 0, stream>>>(counts);
        bin_rows<<<bin_blocks, 256, 0, stream>>>(rois, counts, slots, H, N);
        roialign_binned<<<NBINS * BPB, 1024, 0, stream>>>(
            feat, rois, out, counts, slots, H, W, C / 4, N);
    } else {
        const int rows_per_batch   = N * POOL;
        const int blocks_per_batch = (rows_per_batch + 3) / 4;
        const int slots_g  = (blocks_per_batch + 3) / 4;
        roialign_direct<<<slots_g * 8, 256, 0, stream>>>(
            feat, rois, out, H, W, C / 4, N, blocks_per_batch);
    }
}